// Round 3
// baseline (147.571 us; speedup 1.0000x reference)
//
#include <hip/hip_runtime.h>
#include <math.h>

#define HDIM 128
#define WDIM 128
#define CDIM 64
#define BDIM 4
#define NPIX (BDIM * HDIM * WDIM)   // 65536

// ---------------------------------------------------------------------------
// Kernel 1: dual 1x1 conv (per-pixel channel matmul), fp32 vector ALU.
//   (unchanged — isolating the attn fix this round; conv gets profiled next)
// ---------------------------------------------------------------------------
__global__ void conv1x1_kernel(const float* __restrict__ xm,
                               const float* __restrict__ xr,
                               const float* __restrict__ Wm,
                               const float* __restrict__ Wr,
                               float* __restrict__ outm,
                               float* __restrict__ outr) {
    const float* x; const float* Wg; float* out;
    if (blockIdx.y == 0) { x = xm; Wg = Wm; out = outm; }
    else                 { x = xr; Wg = Wr; out = outr; }

    __shared__ float Ws[CDIM][CDIM];   // [c][d]
    __shared__ float xs[CDIM][132];    // [c][px] padded

    const int t = threadIdx.x;
    const int pxbase = blockIdx.x * 128;

    {
        const float4* Wg4 = (const float4*)Wg;
        float4* Ws4 = (float4*)&Ws[0][0];
        #pragma unroll
        for (int i = 0; i < 4; ++i) Ws4[t + 256 * i] = Wg4[t + 256 * i];
    }
    #pragma unroll
    for (int i = 0; i < 8; ++i) {
        int L  = t + 256 * i;
        int px = L >> 4;
        int c4 = L & 15;
        float4 v = *(const float4*)&x[(size_t)(pxbase + px) * CDIM + 4 * c4];
        xs[4 * c4 + 0][px] = v.x;
        xs[4 * c4 + 1][px] = v.y;
        xs[4 * c4 + 2][px] = v.z;
        xs[4 * c4 + 3][px] = v.w;
    }
    __syncthreads();

    const int dg = t & 7;
    const int pg = t >> 3;

    float acc[4][8];
    #pragma unroll
    for (int i = 0; i < 4; ++i)
        #pragma unroll
        for (int j = 0; j < 8; ++j) acc[i][j] = 0.f;

    #pragma unroll 16
    for (int c = 0; c < CDIM; ++c) {
        float4 xv = *(const float4*)&xs[c][pg * 4];
        float4 w0 = *(const float4*)&Ws[c][dg * 8];
        float4 w1 = *(const float4*)&Ws[c][dg * 8 + 4];
        float xa[4] = {xv.x, xv.y, xv.z, xv.w};
        float wa[8] = {w0.x, w0.y, w0.z, w0.w, w1.x, w1.y, w1.z, w1.w};
        #pragma unroll
        for (int i = 0; i < 4; ++i)
            #pragma unroll
            for (int j = 0; j < 8; ++j)
                acc[i][j] = fmaf(xa[i], wa[j], acc[i][j]);
    }

    #pragma unroll
    for (int i = 0; i < 4; ++i) {
        int px = pxbase + pg * 4 + i;
        float4 o0 = {acc[i][0], acc[i][1], acc[i][2], acc[i][3]};
        float4 o1 = {acc[i][4], acc[i][5], acc[i][6], acc[i][7]};
        *(float4*)&out[(size_t)px * CDIM + dg * 8]     = o0;
        *(float4*)&out[(size_t)px * CDIM + dg * 8 + 4] = o1;
    }
}

// ---------------------------------------------------------------------------
// Kernel 2 (v3): LDS-tiled scores + softmax, LDS <= 64 KB this time.
//   Block = 16(w) x 8(h) pixel tile, 256 threads = 2 threads/pixel (channel
//   halves). cr halo (20x12 px, zero-padded at borders) staged in LDS with
//   pixel stride 66 floats (66 % 32 == 2 -> b128 bank windows rotate 2
//   banks/pixel, uniform 8 accesses/bank = b128 floor). 63,360 B static LDS
//   (round 1 used 108.8 KB -> silent launch failure; 64 KB is the API cap).
// ---------------------------------------------------------------------------
#define TILE_W 16
#define TILE_H 8
#define HALO_W 20               // TILE_W + 4
#define HALO_H 12               // TILE_H + 4
#define NHALO (HALO_W * HALO_H) // 240
#define PSTRIDE 66              // floats per halo pixel in LDS

__global__ __launch_bounds__(256, 1)
void attn_tiled_kernel(const float* __restrict__ cm,
                       const float* __restrict__ cr,
                       float* __restrict__ out) {
    __shared__ float crs[NHALO * PSTRIDE];   // 63,360 B

    const int t   = threadIdx.x;
    const int tx0 = blockIdx.x * TILE_W;
    const int ty0 = blockIdx.y * TILE_H;
    const int b   = blockIdx.z;

    // ---- stage cr halo tile: 240 px x 16 float4 = 3840 float4, 15 iters ----
    #pragma unroll
    for (int it = 0; it < 15; ++it) {
        int L   = t + 256 * it;
        int pix = L >> 4;                   // 0..239
        int q   = L & 15;                   // float4 chunk within pixel
        int hy  = pix / HALO_W;
        int hx  = pix - hy * HALO_W;
        int gy  = ty0 + hy - 2, gx = tx0 + hx - 2;
        float4 v = make_float4(0.f, 0.f, 0.f, 0.f);
        if (gy >= 0 && gy < HDIM && gx >= 0 && gx < WDIM) {
            size_t gp = ((size_t)b * HDIM + gy) * WDIM + gx;
            v = *(const float4*)&cr[gp * CDIM + 4 * q];
        }
        *(float4*)&crs[pix * PSTRIDE + 4 * q] = v;
    }
    __syncthreads();

    // ---- per-thread: one pixel, one channel half ----
    const int pl = t >> 1;                  // local pixel 0..127
    const int cg = t & 1;                   // channel half
    const int lx = pl & (TILE_W - 1);
    const int ly = pl >> 4;                 // 0..7
    const size_t gpx = ((size_t)b * HDIM + ty0 + ly) * WDIM + tx0 + lx;

    float4 qv[8];
    {
        const float4* cmp = (const float4*)&cm[gpx * CDIM + cg * 32];
        #pragma unroll
        for (int m = 0; m < 8; ++m) qv[m] = cmp[m];
    }

    float s[26];
    #pragma unroll
    for (int k = 0; k < 25; ++k) {
        const int i = k / 5, j = k % 5;
        const int p = (ly + i) * HALO_W + (lx + j);
        const float4* kp = (const float4*)&crs[p * PSTRIDE + cg * 32];
        float acc = 0.f;
        #pragma unroll
        for (int m = 0; m < 8; ++m) {
            float4 v = kp[m];
            acc = fmaf(qv[m].x, v.x, acc);
            acc = fmaf(qv[m].y, v.y, acc);
            acc = fmaf(qv[m].z, v.z, acc);
            acc = fmaf(qv[m].w, v.w, acc);
        }
        s[k] = acc;
    }
    {
        float acc = 0.f;
        #pragma unroll
        for (int m = 0; m < 8; ++m) {
            float4 v = qv[m];
            acc = fmaf(v.x, v.x, acc);
            acc = fmaf(v.y, v.y, acc);
            acc = fmaf(v.z, v.z, acc);
            acc = fmaf(v.w, v.w, acc);
        }
        s[25] = acc;
    }

    // combine channel halves (lanes 2k/2k+1 hold same pixel)
    #pragma unroll
    for (int k = 0; k < 26; ++k) s[k] += __shfl_xor(s[k], 1);

    // softmax over 26 (both lanes compute; each writes 13)
    float mx = s[0];
    #pragma unroll
    for (int k = 1; k < 26; ++k) mx = fmaxf(mx, s[k]);
    float sum = 0.f;
    #pragma unroll
    for (int k = 0; k < 26; ++k) { s[k] = __expf(s[k] - mx); sum += s[k]; }
    const float inv = 1.f / sum;

    float* op = &out[gpx * 26 + cg * 13];
    const int kb = cg * 13;
    #pragma unroll
    for (int k = 0; k < 13; ++k) op[k] = s[kb + k] * inv;
}

// ---------------------------------------------------------------------------
extern "C" void kernel_launch(void* const* d_in, const int* in_sizes, int n_in,
                              void* d_out, int out_size, void* d_ws, size_t ws_size,
                              hipStream_t stream) {
    const float* xm = (const float*)d_in[0];
    const float* xr = (const float*)d_in[1];
    const float* Wm = (const float*)d_in[2];
    const float* Wr = (const float*)d_in[3];
    float* outp = (float*)d_out;

    float* cm = (float*)d_ws;
    float* cr = cm + (size_t)NPIX * CDIM;

    dim3 g1(NPIX / 128, 2);
    conv1x1_kernel<<<g1, 256, 0, stream>>>(xm, xr, Wm, Wr, cm, cr);

    dim3 g2(WDIM / TILE_W, HDIM / TILE_H, BDIM);   // 8 x 16 x 4 = 512 blocks
    attn_tiled_kernel<<<g2, 256, 0, stream>>>(cm, cr, outp);
}

// Round 4
// 107.126 us; speedup vs baseline: 1.3775x; 1.3775x over previous
//
#include <hip/hip_runtime.h>
#include <math.h>

#define HDIM 128
#define WDIM 128
#define CDIM 64
#define BDIM 4
#define NPIX (BDIM * HDIM * WDIM)   // 65536

// ---------------------------------------------------------------------------
// Kernel 1: dual 1x1 conv (per-pixel channel matmul), fp32 vector ALU.
//   (unchanged — isolating the attn scratch-fix this round)
// ---------------------------------------------------------------------------
__global__ void conv1x1_kernel(const float* __restrict__ xm,
                               const float* __restrict__ xr,
                               const float* __restrict__ Wm,
                               const float* __restrict__ Wr,
                               float* __restrict__ outm,
                               float* __restrict__ outr) {
    const float* x; const float* Wg; float* out;
    if (blockIdx.y == 0) { x = xm; Wg = Wm; out = outm; }
    else                 { x = xr; Wg = Wr; out = outr; }

    __shared__ float Ws[CDIM][CDIM];   // [c][d]
    __shared__ float xs[CDIM][132];    // [c][px] padded

    const int t = threadIdx.x;
    const int pxbase = blockIdx.x * 128;

    {
        const float4* Wg4 = (const float4*)Wg;
        float4* Ws4 = (float4*)&Ws[0][0];
        #pragma unroll
        for (int i = 0; i < 4; ++i) Ws4[t + 256 * i] = Wg4[t + 256 * i];
    }
    #pragma unroll
    for (int i = 0; i < 8; ++i) {
        int L  = t + 256 * i;
        int px = L >> 4;
        int c4 = L & 15;
        float4 v = *(const float4*)&x[(size_t)(pxbase + px) * CDIM + 4 * c4];
        xs[4 * c4 + 0][px] = v.x;
        xs[4 * c4 + 1][px] = v.y;
        xs[4 * c4 + 2][px] = v.z;
        xs[4 * c4 + 3][px] = v.w;
    }
    __syncthreads();

    const int dg = t & 7;
    const int pg = t >> 3;

    float acc[4][8];
    #pragma unroll
    for (int i = 0; i < 4; ++i)
        #pragma unroll
        for (int j = 0; j < 8; ++j) acc[i][j] = 0.f;

    #pragma unroll 16
    for (int c = 0; c < CDIM; ++c) {
        float4 xv = *(const float4*)&xs[c][pg * 4];
        float4 w0 = *(const float4*)&Ws[c][dg * 8];
        float4 w1 = *(const float4*)&Ws[c][dg * 8 + 4];
        float xa[4] = {xv.x, xv.y, xv.z, xv.w};
        float wa[8] = {w0.x, w0.y, w0.z, w0.w, w1.x, w1.y, w1.z, w1.w};
        #pragma unroll
        for (int i = 0; i < 4; ++i)
            #pragma unroll
            for (int j = 0; j < 8; ++j)
                acc[i][j] = fmaf(xa[i], wa[j], acc[i][j]);
    }

    #pragma unroll
    for (int i = 0; i < 4; ++i) {
        int px = pxbase + pg * 4 + i;
        float4 o0 = {acc[i][0], acc[i][1], acc[i][2], acc[i][3]};
        float4 o1 = {acc[i][4], acc[i][5], acc[i][6], acc[i][7]};
        *(float4*)&out[(size_t)px * CDIM + dg * 8]     = o0;
        *(float4*)&out[(size_t)px * CDIM + dg * 8 + 4] = o1;
    }
}

// ---------------------------------------------------------------------------
// Kernel 2 (v4): LDS-tiled scores + softmax, scores kept in VGPRs.
//   ROUND-3 BUG FIX: the final store indexed s[cg*13 + k] with runtime cg ->
//   compiler allocated s[26] in SCRATCH -> every accumulation/softmax access
//   was a private-memory round-trip (the 65 us latency wall; VGPR=88 was the
//   tell). Now all s[] indices are compile-time (branch on cg, each branch
//   fully unrolled) so s lives in registers.
//   PSTRIDE 66 -> 68: 16-B-aligned pixel rows (real ds_*_b128), stride 4 mod
//   32 -> uniform 8 dword-accesses/bank = b128 floor. LDS 65,280 B (<=64 KB
//   API cap; 2 blocks/CU).
// ---------------------------------------------------------------------------
#define TILE_W 16
#define TILE_H 8
#define HALO_W 20               // TILE_W + 4
#define HALO_H 12               // TILE_H + 4
#define NHALO (HALO_W * HALO_H) // 240
#define PSTRIDE 68              // floats per halo pixel in LDS (16-B aligned)

__global__ __launch_bounds__(256, 1)
void attn_tiled_kernel(const float* __restrict__ cm,
                       const float* __restrict__ cr,
                       float* __restrict__ out) {
    __shared__ float crs[NHALO * PSTRIDE];   // 65,280 B

    const int t   = threadIdx.x;
    const int tx0 = blockIdx.x * TILE_W;
    const int ty0 = blockIdx.y * TILE_H;
    const int b   = blockIdx.z;

    // ---- stage cr halo tile: 240 px x 16 float4 = 3840 float4, 15 iters ----
    #pragma unroll
    for (int it = 0; it < 15; ++it) {
        int L   = t + 256 * it;
        int pix = L >> 4;                   // 0..239
        int q   = L & 15;                   // float4 chunk within pixel
        int hy  = pix / HALO_W;
        int hx  = pix - hy * HALO_W;
        int gy  = ty0 + hy - 2, gx = tx0 + hx - 2;
        float4 v = make_float4(0.f, 0.f, 0.f, 0.f);
        if (gy >= 0 && gy < HDIM && gx >= 0 && gx < WDIM) {
            size_t gp = ((size_t)b * HDIM + gy) * WDIM + gx;
            v = *(const float4*)&cr[gp * CDIM + 4 * q];
        }
        *(float4*)&crs[pix * PSTRIDE + 4 * q] = v;
    }
    __syncthreads();

    // ---- per-thread: one pixel, one channel half ----
    const int pl = t >> 1;                  // local pixel 0..127
    const int cg = t & 1;                   // channel half
    const int lx = pl & (TILE_W - 1);
    const int ly = pl >> 4;                 // 0..7
    const size_t gpx = ((size_t)b * HDIM + ty0 + ly) * WDIM + tx0 + lx;

    float4 qv[8];
    {
        const float4* cmp = (const float4*)&cm[gpx * CDIM + cg * 32];
        #pragma unroll
        for (int m = 0; m < 8; ++m) qv[m] = cmp[m];
    }

    float s[26];
    #pragma unroll
    for (int k = 0; k < 25; ++k) {
        const int i = k / 5, j = k % 5;
        const int p = (ly + i) * HALO_W + (lx + j);
        const float4* kp = (const float4*)&crs[p * PSTRIDE + cg * 32];
        float acc = 0.f;
        #pragma unroll
        for (int m = 0; m < 8; ++m) {
            float4 v = kp[m];
            acc = fmaf(qv[m].x, v.x, acc);
            acc = fmaf(qv[m].y, v.y, acc);
            acc = fmaf(qv[m].z, v.z, acc);
            acc = fmaf(qv[m].w, v.w, acc);
        }
        s[k] = acc;
    }
    {
        float acc = 0.f;
        #pragma unroll
        for (int m = 0; m < 8; ++m) {
            float4 v = qv[m];
            acc = fmaf(v.x, v.x, acc);
            acc = fmaf(v.y, v.y, acc);
            acc = fmaf(v.z, v.z, acc);
            acc = fmaf(v.w, v.w, acc);
        }
        s[25] = acc;
    }

    // combine channel halves (lanes 2k/2k+1 hold same pixel)
    #pragma unroll
    for (int k = 0; k < 26; ++k) s[k] += __shfl_xor(s[k], 1);

    // softmax over 26 (both lanes compute; each writes 13)
    float mx = s[0];
    #pragma unroll
    for (int k = 1; k < 26; ++k) mx = fmaxf(mx, s[k]);
    float sum = 0.f;
    #pragma unroll
    for (int k = 0; k < 26; ++k) { s[k] = __expf(s[k] - mx); sum += s[k]; }
    const float inv = 1.f / sum;

    // ALL indices compile-time constant -> s[] stays in VGPRs.
    float* op = &out[gpx * 26 + cg * 13];
    if (cg == 0) {
        #pragma unroll
        for (int k = 0; k < 13; ++k) op[k] = s[k] * inv;
    } else {
        #pragma unroll
        for (int k = 0; k < 13; ++k) op[k] = s[13 + k] * inv;
    }
}

// ---------------------------------------------------------------------------
extern "C" void kernel_launch(void* const* d_in, const int* in_sizes, int n_in,
                              void* d_out, int out_size, void* d_ws, size_t ws_size,
                              hipStream_t stream) {
    const float* xm = (const float*)d_in[0];
    const float* xr = (const float*)d_in[1];
    const float* Wm = (const float*)d_in[2];
    const float* Wr = (const float*)d_in[3];
    float* outp = (float*)d_out;

    float* cm = (float*)d_ws;
    float* cr = cm + (size_t)NPIX * CDIM;

    dim3 g1(NPIX / 128, 2);
    conv1x1_kernel<<<g1, 256, 0, stream>>>(xm, xr, Wm, Wr, cm, cr);

    dim3 g2(WDIM / TILE_W, HDIM / TILE_H, BDIM);   // 8 x 16 x 4 = 512 blocks
    attn_tiled_kernel<<<g2, 256, 0, stream>>>(cm, cr, outp);
}